// Round 1
// baseline (2783.743 us; speedup 1.0000x reference)
//
#include <hip/hip_runtime.h>
#include <hip/hip_bf16.h>
#include <stdint.h>

typedef __bf16 bf16x8 __attribute__((ext_vector_type(8)));
typedef float floatx4 __attribute__((ext_vector_type(4)));

__device__ __forceinline__ float bf2f(__hip_bfloat16 v) { return __bfloat162float(v); }
__device__ __forceinline__ __hip_bfloat16 f2bf(float v) { return __float2bfloat16(v); }

// ---------------- elementwise: fp32 -> bf16 cast ----------------
__global__ __launch_bounds__(256) void k_f2bf(const float* __restrict__ in,
                                              __hip_bfloat16* __restrict__ out, int n) {
    int i = blockIdx.x * 256 + threadIdx.x;
    if (i < n) out[i] = f2bf(in[i]);
}

// ---------------- LayerNorm: one block per row, bf16 out ----------------
__global__ __launch_bounds__(256) void k_ln(const float* __restrict__ x,
                                            const float* __restrict__ w,
                                            const float* __restrict__ b,
                                            __hip_bfloat16* __restrict__ out, int d) {
    __shared__ float red[8];
    const size_t row = blockIdx.x;
    const float* xr = x + row * (size_t)d;
    float s = 0.f, ss = 0.f;
    for (int i = threadIdx.x; i < d; i += 256) {
        float v = xr[i];
        s += v; ss += v * v;
    }
    for (int off = 32; off > 0; off >>= 1) {
        s  += __shfl_down(s,  off, 64);
        ss += __shfl_down(ss, off, 64);
    }
    int wv = threadIdx.x >> 6, ln = threadIdx.x & 63;
    if (ln == 0) { red[wv] = s; red[4 + wv] = ss; }
    __syncthreads();
    s  = red[0] + red[1] + red[2] + red[3];
    ss = red[4] + red[5] + red[6] + red[7];
    float mu  = s / d;
    float var = ss / d - mu * mu;
    float rs  = rsqrtf(var + 1e-5f);
    __hip_bfloat16* orow = out + row * (size_t)d;
    for (int i = threadIdx.x; i < d; i += 256) {
        orow[i] = f2bf((xr[i] - mu) * rs * w[i] + b[i]);
    }
}

// ---------------- time-mix prep (shift + mix + sigmoid on r) ----------------
// grid: (d/256, Mrows)
__global__ __launch_bounds__(256) void k_tmix(const __hip_bfloat16* __restrict__ xln,
    const float* __restrict__ mk, const float* __restrict__ mv, const float* __restrict__ mr,
    __hip_bfloat16* __restrict__ xk, __hip_bfloat16* __restrict__ xv, __hip_bfloat16* __restrict__ xr,
    int T, int d) {
    const int c = blockIdx.x * 256 + threadIdx.x;
    const size_t row = blockIdx.y;
    const int t = (int)(row % (size_t)T);   // scalar per block
    const size_t idx = row * (size_t)d + c;
    float xc = bf2f(xln[idx]);
    float xs = t ? bf2f(xln[idx - d]) : 0.f;
    float a = mk[c];
    xk[idx] = f2bf(xc * a + xs * (1.f - a));
    float bq = mv[c];
    xv[idx] = f2bf(xc * bq + xs * (1.f - bq));
    float rm = mr[c];
    float pre = xc * rm + xs * (1.f - rm);
    xr[idx] = f2bf(1.f / (1.f + __expf(-pre)));   // sigmoid BEFORE Wr gemm (per reference)
}

// ---------------- channel-mix prep (shift + mix, no sigmoid) ----------------
__global__ __launch_bounds__(256) void k_cmix(const __hip_bfloat16* __restrict__ xln,
    const float* __restrict__ mk, const float* __restrict__ mr,
    __hip_bfloat16* __restrict__ xk, __hip_bfloat16* __restrict__ xr,
    int T, int d) {
    const int c = blockIdx.x * 256 + threadIdx.x;
    const size_t row = blockIdx.y;
    const int t = (int)(row % (size_t)T);
    const size_t idx = row * (size_t)d + c;
    float xc = bf2f(xln[idx]);
    float xs = t ? bf2f(xln[idx - d]) : 0.f;
    float a = mk[c];
    xk[idx] = f2bf(xc * a + xs * (1.f - a));
    float rm = mr[c];
    xr[idx] = f2bf(xc * rm + xs * (1.f - rm));
}

// ---------------- WKV serial scan over T, fused r multiply ----------------
// one thread per (b, c); out may alias v (per-element read-before-write, no restrict)
__global__ __launch_bounds__(256) void k_wkv(const __hip_bfloat16* __restrict__ k,
    const __hip_bfloat16* v,
    const __hip_bfloat16* __restrict__ r,
    const float* __restrict__ u, const float* __restrict__ w,
    __hip_bfloat16* out, int T, int d) {
    const int gid = blockIdx.x * 256 + threadIdx.x;   // b*d + c
    const int c = gid % d;
    const int b = gid / d;
    const float uc = u[c], wc = w[c];
    float aa = 0.f, bb = 0.f;
    const size_t base = (size_t)b * (size_t)T * (size_t)d + c;
    float kt = bf2f(k[base]);
    float vt = bf2f(v[base]);
    float rt = bf2f(r[base]);
    for (int t = 0; t < T; ++t) {
        size_t nxt = base + (size_t)((t + 1 < T) ? (t + 1) : 0) * d;  // prefetch (wraps harmlessly)
        float kn = bf2f(k[nxt]);
        float vn = bf2f(v[nxt]);
        float rn = bf2f(r[nxt]);
        float q  = fmaxf(uc + kt, wc);
        float e1 = __expf(-wc - q);
        float e2 = __expf(uc + kt - q);
        aa = e1 * aa + e2 * vt;
        bb = e1 * bb + e2;
        out[base + (size_t)t * d] = f2bf((aa / bb) * rt);
        kt = kn; vt = vn; rt = rn;
    }
}

// ---------------- bf16 MFMA GEMM: C[M,N] = A[M,K] @ B[N,K]^T ----------------
// 128x128 tile, BK=32, 4 waves (2x2), each wave 64x64 = 4x4 MFMA 16x16x32 tiles.
// Staging via global_load_lds width=16 (wave-uniform LDS base + lane*16).
#define GM_BF16  0   // store bf16(acc)
#define GM_ADDX  1   // store fp32: auxf[idx] + bias[col] + acc   (x + att)
#define GM_SIG   2   // store bf16(sigmoid(acc))
#define GM_RELU2 3   // store bf16(relu(acc)^2)
#define GM_FINAL 4   // fp32 out[idx] += bf2f(auxb[idx]) * acc    (x1 + r*v)

template<int MODE>
__global__ __launch_bounds__(256, 2)
void gemm_bt(const __hip_bfloat16* __restrict__ A,
             const __hip_bfloat16* __restrict__ B,
             void* __restrict__ outv,
             const float* __restrict__ auxf,
             const float* __restrict__ bias,
             const __hip_bfloat16* __restrict__ auxb,
             int N, int K) {
    __shared__ unsigned short As[128 * 32];
    __shared__ unsigned short Bs[128 * 32];
    const int tid  = threadIdx.x;
    const int lane = tid & 63;
    const int wave = tid >> 6;          // 0..3
    const int waveM = (wave >> 1) << 6; // 0 or 64
    const int waveN = (wave & 1) << 6;
    const int bm = blockIdx.y * 128;
    const int bn = blockIdx.x * 128;

    // staging geometry: wave handles 2 chunks of 16 rows for A and for B
    const int srow = lane >> 2;          // 0..15
    const int scol = (lane & 3) << 3;    // 0,8,16,24 (elements)
    const __hip_bfloat16* Ag = A + (size_t)(bm + wave * 32 + srow) * K + scol;
    const __hip_bfloat16* Bg = B + (size_t)(bn + wave * 32 + srow) * K + scol;
    unsigned short* As0 = As + wave * 1024;        // chunk base (wave-uniform)
    unsigned short* Bs0 = Bs + wave * 1024;

    floatx4 acc[4][4] = {};
    const int aoff = ((lane & 15) * 32) + ((lane >> 4) << 3);  // frag element offset

    for (int k0 = 0; k0 < K; k0 += 32) {
        __builtin_amdgcn_global_load_lds(
            (__attribute__((address_space(1))) void*)(Ag + k0),
            (__attribute__((address_space(3))) void*)(As0), 16, 0, 0);
        __builtin_amdgcn_global_load_lds(
            (__attribute__((address_space(1))) void*)(Ag + k0 + (size_t)16 * K),
            (__attribute__((address_space(3))) void*)(As0 + 512), 16, 0, 0);
        __builtin_amdgcn_global_load_lds(
            (__attribute__((address_space(1))) void*)(Bg + k0),
            (__attribute__((address_space(3))) void*)(Bs0), 16, 0, 0);
        __builtin_amdgcn_global_load_lds(
            (__attribute__((address_space(1))) void*)(Bg + k0 + (size_t)16 * K),
            (__attribute__((address_space(3))) void*)(Bs0 + 512), 16, 0, 0);
        __syncthreads();
        bf16x8 af[4], bfr[4];
#pragma unroll
        for (int i = 0; i < 4; ++i) {
            af[i]  = *reinterpret_cast<const bf16x8*>(As + (waveM + i * 16) * 32 + aoff);
            bfr[i] = *reinterpret_cast<const bf16x8*>(Bs + (waveN + i * 16) * 32 + aoff);
        }
#pragma unroll
        for (int mt = 0; mt < 4; ++mt)
#pragma unroll
            for (int nt = 0; nt < 4; ++nt)
                acc[mt][nt] = __builtin_amdgcn_mfma_f32_16x16x32_bf16(af[mt], bfr[nt], acc[mt][nt], 0, 0, 0);
        __syncthreads();
    }

    // epilogue: C/D layout col=lane&15, row=quad*4+reg
    const int colb = bn + waveN + (lane & 15);
    const int rowb = bm + waveM + ((lane >> 4) << 2);
#pragma unroll
    for (int mt = 0; mt < 4; ++mt) {
#pragma unroll
        for (int nt = 0; nt < 4; ++nt) {
            const int c = colb + nt * 16;
#pragma unroll
            for (int j = 0; j < 4; ++j) {
                const int row = rowb + mt * 16 + j;
                const size_t idx = (size_t)row * N + c;
                const float val = acc[mt][nt][j];
                if (MODE == GM_BF16) {
                    ((__hip_bfloat16*)outv)[idx] = f2bf(val);
                } else if (MODE == GM_ADDX) {
                    ((float*)outv)[idx] = auxf[idx] + bias[c] + val;
                } else if (MODE == GM_SIG) {
                    ((__hip_bfloat16*)outv)[idx] = f2bf(1.f / (1.f + __expf(-val)));
                } else if (MODE == GM_RELU2) {
                    float tpos = fmaxf(val, 0.f);
                    ((__hip_bfloat16*)outv)[idx] = f2bf(tpos * tpos);
                } else {
                    float* o = (float*)outv;
                    o[idx] = o[idx] + bf2f(auxb[idx]) * val;
                }
            }
        }
    }
}

// ---------------- launch ----------------
extern "C" void kernel_launch(void* const* d_in, const int* in_sizes, int n_in,
                              void* d_out, int out_size, void* d_ws, size_t ws_size,
                              hipStream_t stream) {
    const float* x      = (const float*)d_in[0];
    const float* ln1_w  = (const float*)d_in[1];
    const float* ln1_b  = (const float*)d_in[2];
    const float* ln2_w  = (const float*)d_in[3];
    const float* ln2_b  = (const float*)d_in[4];
    const float* tm_u   = (const float*)d_in[5];
    const float* tm_w   = (const float*)d_in[6];
    const float* tm_mk  = (const float*)d_in[7];
    const float* tm_mv  = (const float*)d_in[8];
    const float* tm_mr  = (const float*)d_in[9];
    const float* tm_bo  = (const float*)d_in[14];
    const float* cm_mk  = (const float*)d_in[15];
    const float* cm_mr  = (const float*)d_in[16];

    const int D = in_sizes[1];           // 2048
    const int Mrows = in_sizes[0] / D;   // 16384
    const int T = 2048;
    const int Bb = Mrows / T;            // 8
    const size_t dd = (size_t)D * D;
    const size_t md = (size_t)Mrows * D;

    __hip_bfloat16* W = (__hip_bfloat16*)d_ws;     // 7 weights, bf16
    __hip_bfloat16* buf[7];
    for (int i = 0; i < 7; ++i) buf[i] = W + 7 * dd + (size_t)i * md;
    // buf0: xln -> x2ln ; buf1: xk -> xk2 ; buf2: xv -> xr2 ; buf3: xr -> r2s
    // buf4: k ; buf5: v -> wkv*r ; buf6: r -> k2

    // 1) weights -> bf16   (slots: 0 Wk,1 Wv,2 Wr,3 Wo,4 cmWk,5 cmWv,6 cmWr)
    const int widx[7] = {10, 11, 12, 13, 17, 18, 19};
    for (int i = 0; i < 7; ++i)
        k_f2bf<<<(int)(dd / 256), 256, 0, stream>>>((const float*)d_in[widx[i]], W + (size_t)i * dd, (int)dd);

    // 2) ln1
    k_ln<<<Mrows, 256, 0, stream>>>(x, ln1_w, ln1_b, buf[0], D);
    // 3) time-mix prep
    k_tmix<<<dim3(D / 256, Mrows), 256, 0, stream>>>(buf[0], tm_mk, tm_mv, tm_mr,
                                                     buf[1], buf[2], buf[3], T, D);
    dim3 gg(D / 128, Mrows / 128);
    // 4) k, v, r gemms
    gemm_bt<GM_BF16><<<gg, 256, 0, stream>>>(buf[1], W + 0 * dd, buf[4], nullptr, nullptr, nullptr, D, D);
    gemm_bt<GM_BF16><<<gg, 256, 0, stream>>>(buf[2], W + 1 * dd, buf[5], nullptr, nullptr, nullptr, D, D);
    gemm_bt<GM_BF16><<<gg, 256, 0, stream>>>(buf[3], W + 2 * dd, buf[6], nullptr, nullptr, nullptr, D, D);
    // 5) wkv scan (writes wkv*r into buf5, in place over v)
    k_wkv<<<(Bb * D) / 256, 256, 0, stream>>>(buf[4], buf[5], buf[6], tm_u, tm_w, buf[5], T, D);
    // 6) att out + residual: d_out = x + (wkv*r)@Wo^T + bo
    gemm_bt<GM_ADDX><<<gg, 256, 0, stream>>>(buf[5], W + 3 * dd, d_out, x, tm_bo, nullptr, D, D);
    // 7) ln2 on x1 (= d_out)
    k_ln<<<Mrows, 256, 0, stream>>>((const float*)d_out, ln2_w, ln2_b, buf[0], D);
    // 8) channel-mix prep
    k_cmix<<<dim3(D / 256, Mrows), 256, 0, stream>>>(buf[0], cm_mk, cm_mr, buf[1], buf[2], T, D);
    // 9) r2 = sigmoid(xr2 @ cmWr^T)  -> bf16
    gemm_bt<GM_SIG><<<gg, 256, 0, stream>>>(buf[2], W + 6 * dd, buf[3], nullptr, nullptr, nullptr, D, D);
    // 10) k2 = relu(xk2 @ cmWk^T)^2  -> bf16
    gemm_bt<GM_RELU2><<<gg, 256, 0, stream>>>(buf[1], W + 4 * dd, buf[6], nullptr, nullptr, nullptr, D, D);
    // 11) d_out += r2s * (k2 @ cmWv^T)
    gemm_bt<GM_FINAL><<<gg, 256, 0, stream>>>(buf[6], W + 5 * dd, d_out, nullptr, nullptr, buf[3], D, D);
}

// Round 2
// 1953.596 us; speedup vs baseline: 1.4249x; 1.4249x over previous
//
#include <hip/hip_runtime.h>
#include <hip/hip_bf16.h>
#include <stdint.h>

typedef __bf16 bf16x8 __attribute__((ext_vector_type(8)));
typedef float floatx4 __attribute__((ext_vector_type(4)));

__device__ __forceinline__ float bf2f(__hip_bfloat16 v) { return __bfloat162float(v); }
__device__ __forceinline__ __hip_bfloat16 f2bf(float v) { return __float2bfloat16(v); }

#define WKV_CH 64   // chunk length for the scan decomposition

// ---------------- elementwise: fp32 -> bf16 cast ----------------
__global__ __launch_bounds__(256) void k_f2bf(const float* __restrict__ in,
                                              __hip_bfloat16* __restrict__ out, int n) {
    int i = blockIdx.x * 256 + threadIdx.x;
    if (i < n) out[i] = f2bf(in[i]);
}

// ---------------- LayerNorm: one block per row, bf16 out ----------------
__global__ __launch_bounds__(256) void k_ln(const float* __restrict__ x,
                                            const float* __restrict__ w,
                                            const float* __restrict__ b,
                                            __hip_bfloat16* __restrict__ out, int d) {
    __shared__ float red[8];
    const size_t row = blockIdx.x;
    const float* xr = x + row * (size_t)d;
    float s = 0.f, ss = 0.f;
    for (int i = threadIdx.x; i < d; i += 256) {
        float v = xr[i];
        s += v; ss += v * v;
    }
    for (int off = 32; off > 0; off >>= 1) {
        s  += __shfl_down(s,  off, 64);
        ss += __shfl_down(ss, off, 64);
    }
    int wv = threadIdx.x >> 6, ln = threadIdx.x & 63;
    if (ln == 0) { red[wv] = s; red[4 + wv] = ss; }
    __syncthreads();
    s  = red[0] + red[1] + red[2] + red[3];
    ss = red[4] + red[5] + red[6] + red[7];
    float mu  = s / d;
    float var = ss / d - mu * mu;
    float rs  = rsqrtf(var + 1e-5f);
    __hip_bfloat16* orow = out + row * (size_t)d;
    for (int i = threadIdx.x; i < d; i += 256) {
        orow[i] = f2bf((xr[i] - mu) * rs * w[i] + b[i]);
    }
}

// ---------------- time-mix prep (shift + mix + sigmoid on r) ----------------
__global__ __launch_bounds__(256) void k_tmix(const __hip_bfloat16* __restrict__ xln,
    const float* __restrict__ mk, const float* __restrict__ mv, const float* __restrict__ mr,
    __hip_bfloat16* __restrict__ xk, __hip_bfloat16* __restrict__ xv, __hip_bfloat16* __restrict__ xr,
    int T, int d) {
    const int c = blockIdx.x * 256 + threadIdx.x;
    const size_t row = blockIdx.y;
    const int t = (int)(row % (size_t)T);
    const size_t idx = row * (size_t)d + c;
    float xc = bf2f(xln[idx]);
    float xs = t ? bf2f(xln[idx - d]) : 0.f;
    float a = mk[c];
    xk[idx] = f2bf(xc * a + xs * (1.f - a));
    float bq = mv[c];
    xv[idx] = f2bf(xc * bq + xs * (1.f - bq));
    float rm = mr[c];
    float pre = xc * rm + xs * (1.f - rm);
    xr[idx] = f2bf(1.f / (1.f + __expf(-pre)));   // sigmoid BEFORE Wr gemm (per reference)
}

// ---------------- channel-mix prep ----------------
__global__ __launch_bounds__(256) void k_cmix(const __hip_bfloat16* __restrict__ xln,
    const float* __restrict__ mk, const float* __restrict__ mr,
    __hip_bfloat16* __restrict__ xk, __hip_bfloat16* __restrict__ xr,
    int T, int d) {
    const int c = blockIdx.x * 256 + threadIdx.x;
    const size_t row = blockIdx.y;
    const int t = (int)(row % (size_t)T);
    const size_t idx = row * (size_t)d + c;
    float xc = bf2f(xln[idx]);
    float xs = t ? bf2f(xln[idx - d]) : 0.f;
    float a = mk[c];
    xk[idx] = f2bf(xc * a + xs * (1.f - a));
    float rm = mr[c];
    xr[idx] = f2bf(xc * rm + xs * (1.f - rm));
}

// ---------------- WKV chunked scan ----------------
// Pass 1: per (b, c, chunk) scan from zero state -> (Ac, Bc, Pc)
__global__ __launch_bounds__(256) void k_wkv_p1(const __hip_bfloat16* __restrict__ k,
    const __hip_bfloat16* __restrict__ v,
    const float* __restrict__ u, const float* __restrict__ w,
    float* __restrict__ Ac, float* __restrict__ Bc, float* __restrict__ Pc,
    int T, int d, int nch) {
    const int idx = blockIdx.x * 256 + threadIdx.x;
    const int c = idx & (d - 1);
    const int rest = idx / d;
    const int j = rest & (nch - 1);
    const int b = rest / nch;
    const float uc = u[c], wc = w[c];
    float aa = 0.f, bb = 0.f, P = 0.f;
    const size_t base = ((size_t)b * T + (size_t)j * WKV_CH) * d + c;
#pragma unroll 4
    for (int t = 0; t < WKV_CH; ++t) {
        float kt = bf2f(k[base + (size_t)t * d]);
        float vt = bf2f(v[base + (size_t)t * d]);
        float q  = fmaxf(uc + kt, wc);
        float e1 = __expf(-wc - q);
        float e2 = __expf(uc + kt - q);
        aa = e1 * aa + e2 * vt;
        bb = e1 * bb + e2;
        P += wc + q;
    }
    const size_t s = ((size_t)b * nch + j) * d + c;
    Ac[s] = aa; Bc[s] = bb; Pc[s] = P;
}

// Pass 2: per (b, c) sequentially combine chunk states; store incoming state per chunk
__global__ __launch_bounds__(256) void k_wkv_p2(const float* __restrict__ Ac,
    const float* __restrict__ Bc, const float* __restrict__ Pc,
    float* __restrict__ Ain, float* __restrict__ Bin, int d, int nch) {
    const int idx = blockIdx.x * 256 + threadIdx.x;   // b*d + c
    const int c = idx & (d - 1);
    const int b = idx / d;
    float a = 0.f, bbs = 0.f;
    for (int j = 0; j < nch; ++j) {
        const size_t s = ((size_t)b * nch + j) * d + c;
        Ain[s] = a; Bin[s] = bbs;
        float p = __expf(-Pc[s]);
        a   = p * a   + Ac[s];
        bbs = p * bbs + Bc[s];
    }
}

// Pass 3: re-run each chunk from exact incoming state, emit (a/b)*r
// out may alias v: per-element read-before-write by same thread
__global__ __launch_bounds__(256) void k_wkv_p3(const __hip_bfloat16* __restrict__ k,
    const __hip_bfloat16* v,
    const __hip_bfloat16* __restrict__ r,
    const float* __restrict__ u, const float* __restrict__ w,
    const float* __restrict__ Ain, const float* __restrict__ Bin,
    __hip_bfloat16* out, int T, int d, int nch) {
    const int idx = blockIdx.x * 256 + threadIdx.x;
    const int c = idx & (d - 1);
    const int rest = idx / d;
    const int j = rest & (nch - 1);
    const int b = rest / nch;
    const float uc = u[c], wc = w[c];
    const size_t s = ((size_t)b * nch + j) * d + c;
    float aa = Ain[s], bb = Bin[s];
    const size_t base = ((size_t)b * T + (size_t)j * WKV_CH) * d + c;
#pragma unroll 4
    for (int t = 0; t < WKV_CH; ++t) {
        float kt = bf2f(k[base + (size_t)t * d]);
        float vt = bf2f(v[base + (size_t)t * d]);
        float rt = bf2f(r[base + (size_t)t * d]);
        float q  = fmaxf(uc + kt, wc);
        float e1 = __expf(-wc - q);
        float e2 = __expf(uc + kt - q);
        aa = e1 * aa + e2 * vt;
        bb = e1 * bb + e2;
        out[base + (size_t)t * d] = f2bf((aa / bb) * rt);
    }
}

// ---------------- bf16 MFMA GEMM: C[M,N] = A[M,K] @ B[N,K]^T ----------------
#define GM_BF16  0
#define GM_ADDX  1
#define GM_SIG   2
#define GM_RELU2 3
#define GM_FINAL 4

template<int MODE>
__global__ __launch_bounds__(256, 2)
void gemm_bt(const __hip_bfloat16* __restrict__ A,
             const __hip_bfloat16* __restrict__ B,
             void* __restrict__ outv,
             const float* __restrict__ auxf,
             const float* __restrict__ bias,
             const __hip_bfloat16* __restrict__ auxb,
             int N, int K) {
    __shared__ unsigned short As[128 * 32];
    __shared__ unsigned short Bs[128 * 32];
    const int tid  = threadIdx.x;
    const int lane = tid & 63;
    const int wave = tid >> 6;
    const int waveM = (wave >> 1) << 6;
    const int waveN = (wave & 1) << 6;
    const int bm = blockIdx.y * 128;
    const int bn = blockIdx.x * 128;

    const int srow = lane >> 2;
    const int scol = (lane & 3) << 3;
    const __hip_bfloat16* Ag = A + (size_t)(bm + wave * 32 + srow) * K + scol;
    const __hip_bfloat16* Bg = B + (size_t)(bn + wave * 32 + srow) * K + scol;
    unsigned short* As0 = As + wave * 1024;
    unsigned short* Bs0 = Bs + wave * 1024;

    floatx4 acc[4][4] = {};
    const int aoff = ((lane & 15) * 32) + ((lane >> 4) << 3);

    for (int k0 = 0; k0 < K; k0 += 32) {
        __builtin_amdgcn_global_load_lds(
            (__attribute__((address_space(1))) void*)(Ag + k0),
            (__attribute__((address_space(3))) void*)(As0), 16, 0, 0);
        __builtin_amdgcn_global_load_lds(
            (__attribute__((address_space(1))) void*)(Ag + k0 + (size_t)16 * K),
            (__attribute__((address_space(3))) void*)(As0 + 512), 16, 0, 0);
        __builtin_amdgcn_global_load_lds(
            (__attribute__((address_space(1))) void*)(Bg + k0),
            (__attribute__((address_space(3))) void*)(Bs0), 16, 0, 0);
        __builtin_amdgcn_global_load_lds(
            (__attribute__((address_space(1))) void*)(Bg + k0 + (size_t)16 * K),
            (__attribute__((address_space(3))) void*)(Bs0 + 512), 16, 0, 0);
        __syncthreads();
        bf16x8 af[4], bfr[4];
#pragma unroll
        for (int i = 0; i < 4; ++i) {
            af[i]  = *reinterpret_cast<const bf16x8*>(As + (waveM + i * 16) * 32 + aoff);
            bfr[i] = *reinterpret_cast<const bf16x8*>(Bs + (waveN + i * 16) * 32 + aoff);
        }
#pragma unroll
        for (int mt = 0; mt < 4; ++mt)
#pragma unroll
            for (int nt = 0; nt < 4; ++nt)
                acc[mt][nt] = __builtin_amdgcn_mfma_f32_16x16x32_bf16(af[mt], bfr[nt], acc[mt][nt], 0, 0, 0);
        __syncthreads();
    }

    const int colb = bn + waveN + (lane & 15);
    const int rowb = bm + waveM + ((lane >> 4) << 2);
#pragma unroll
    for (int mt = 0; mt < 4; ++mt) {
#pragma unroll
        for (int nt = 0; nt < 4; ++nt) {
            const int c = colb + nt * 16;
#pragma unroll
            for (int j = 0; j < 4; ++j) {
                const int row = rowb + mt * 16 + j;
                const size_t idx = (size_t)row * N + c;
                const float val = acc[mt][nt][j];
                if (MODE == GM_BF16) {
                    ((__hip_bfloat16*)outv)[idx] = f2bf(val);
                } else if (MODE == GM_ADDX) {
                    ((float*)outv)[idx] = auxf[idx] + bias[c] + val;
                } else if (MODE == GM_SIG) {
                    ((__hip_bfloat16*)outv)[idx] = f2bf(1.f / (1.f + __expf(-val)));
                } else if (MODE == GM_RELU2) {
                    float tpos = fmaxf(val, 0.f);
                    ((__hip_bfloat16*)outv)[idx] = f2bf(tpos * tpos);
                } else {
                    float* o = (float*)outv;
                    o[idx] = o[idx] + bf2f(auxb[idx]) * val;
                }
            }
        }
    }
}

// ---------------- launch ----------------
extern "C" void kernel_launch(void* const* d_in, const int* in_sizes, int n_in,
                              void* d_out, int out_size, void* d_ws, size_t ws_size,
                              hipStream_t stream) {
    const float* x      = (const float*)d_in[0];
    const float* ln1_w  = (const float*)d_in[1];
    const float* ln1_b  = (const float*)d_in[2];
    const float* ln2_w  = (const float*)d_in[3];
    const float* ln2_b  = (const float*)d_in[4];
    const float* tm_u   = (const float*)d_in[5];
    const float* tm_w   = (const float*)d_in[6];
    const float* tm_mk  = (const float*)d_in[7];
    const float* tm_mv  = (const float*)d_in[8];
    const float* tm_mr  = (const float*)d_in[9];
    const float* tm_bo  = (const float*)d_in[14];
    const float* cm_mk  = (const float*)d_in[15];
    const float* cm_mr  = (const float*)d_in[16];

    const int D = in_sizes[1];           // 2048
    const int Mrows = in_sizes[0] / D;   // 16384
    const int T = 2048;
    const int Bb = Mrows / T;            // 8
    const size_t dd = (size_t)D * D;
    const size_t md = (size_t)Mrows * D;
    const int nch = T / WKV_CH;          // 32

    __hip_bfloat16* W = (__hip_bfloat16*)d_ws;
    __hip_bfloat16* buf[7];
    for (int i = 0; i < 7; ++i) buf[i] = W + 7 * dd + (size_t)i * md;
    // buf0: xln -> (scan scratch) -> x2ln ; buf1: xk -> xk2 ; buf2: xv -> xr2
    // buf3: xr -> r2s ; buf4: k ; buf5: v -> wkv*r ; buf6: r -> k2

    // scan scratch carved from buf0 (dead between k_tmix-consumers and ln2)
    float* S = (float*)buf[0];
    const size_t cs = (size_t)Bb * nch * D;   // 524288 floats = 2 MB
    float* Ac  = S;
    float* Bc  = S + cs;
    float* Pc  = S + 2 * cs;
    float* Ain = S + 3 * cs;
    float* Bin = S + 4 * cs;

    const int widx[7] = {10, 11, 12, 13, 17, 18, 19};
    for (int i = 0; i < 7; ++i)
        k_f2bf<<<(int)(dd / 256), 256, 0, stream>>>((const float*)d_in[widx[i]], W + (size_t)i * dd, (int)dd);

    k_ln<<<Mrows, 256, 0, stream>>>(x, ln1_w, ln1_b, buf[0], D);
    k_tmix<<<dim3(D / 256, Mrows), 256, 0, stream>>>(buf[0], tm_mk, tm_mv, tm_mr,
                                                     buf[1], buf[2], buf[3], T, D);
    dim3 gg(D / 128, Mrows / 128);
    gemm_bt<GM_BF16><<<gg, 256, 0, stream>>>(buf[1], W + 0 * dd, buf[4], nullptr, nullptr, nullptr, D, D);
    gemm_bt<GM_BF16><<<gg, 256, 0, stream>>>(buf[2], W + 1 * dd, buf[5], nullptr, nullptr, nullptr, D, D);
    gemm_bt<GM_BF16><<<gg, 256, 0, stream>>>(buf[3], W + 2 * dd, buf[6], nullptr, nullptr, nullptr, D, D);

    // chunked wkv scan (exact): p1 partial states, p2 combine, p3 emit
    k_wkv_p1<<<(Bb * D * nch) / 256, 256, 0, stream>>>(buf[4], buf[5], tm_u, tm_w,
                                                       Ac, Bc, Pc, T, D, nch);
    k_wkv_p2<<<(Bb * D) / 256, 256, 0, stream>>>(Ac, Bc, Pc, Ain, Bin, D, nch);
    k_wkv_p3<<<(Bb * D * nch) / 256, 256, 0, stream>>>(buf[4], buf[5], buf[6], tm_u, tm_w,
                                                       Ain, Bin, buf[5], T, D, nch);

    gemm_bt<GM_ADDX><<<gg, 256, 0, stream>>>(buf[5], W + 3 * dd, d_out, x, tm_bo, nullptr, D, D);
    k_ln<<<Mrows, 256, 0, stream>>>((const float*)d_out, ln2_w, ln2_b, buf[0], D);
    k_cmix<<<dim3(D / 256, Mrows), 256, 0, stream>>>(buf[0], cm_mk, cm_mr, buf[1], buf[2], T, D);
    gemm_bt<GM_SIG><<<gg, 256, 0, stream>>>(buf[2], W + 6 * dd, buf[3], nullptr, nullptr, nullptr, D, D);
    gemm_bt<GM_RELU2><<<gg, 256, 0, stream>>>(buf[1], W + 4 * dd, buf[6], nullptr, nullptr, nullptr, D, D);
    gemm_bt<GM_FINAL><<<gg, 256, 0, stream>>>(buf[6], W + 5 * dd, d_out, nullptr, nullptr, buf[3], D, D);
}